// Round 3
// baseline (724.876 us; speedup 1.0000x reference)
//
#include <hip/hip_runtime.h>

// GPT-2 block forward, MI355X/gfx950. B=4 T=2048 C=768 H=12 D=64; M=8192.
// Runtime dtype detection: inputs may be fp32 or bf16 (flag in ws).
// Internally bf16 (fp32 accum), residual stream x1 in fp32.
// R2: attention rewritten — V pre-transposed to [bh][d][T] so PV B-frags are
// contiguous global 16B reads; 4-wave blocks, 64-key tiles, no barriers in
// the k-loop (per-wave P buffers).

typedef unsigned short ushortT;
typedef unsigned int uintT;
typedef __attribute__((ext_vector_type(8))) __bf16 bf16x8;
typedef __attribute__((ext_vector_type(4))) float f32x4;

#define MFMA16(a, b, c) __builtin_amdgcn_mfma_f32_16x16x32_bf16(a, b, c, 0, 0, 0)

__device__ inline float b2f(ushortT u) {
  return __uint_as_float(((uintT)u) << 16);
}
__device__ inline ushortT f2b(float f) {  // round-to-nearest-even
  uintT x = __float_as_uint(f);
  uintT r = x + 0x7fffu + ((x >> 16) & 1u);
  return (ushortT)(r >> 16);
}

__device__ inline float gelu_tanh(float v) {
  float t = 0.7978845608028654f * (v + 0.044715f * v * v * v);
  return v / (1.0f + __expf(-2.0f * t));
}

// ------------------------------------------------------------- dtype detect
__global__ __launch_bounds__(256) void detect_dtype(
    const ushortT* __restrict__ w, int* __restrict__ flag) {
  __shared__ int red;
  if (threadIdx.x == 0) red = 0;
  __syncthreads();
  int crazy = 0;
  for (int i = threadIdx.x; i < 4096; i += 256) {
    uintT e = (w[2 * i] >> 7) & 0xFF;
    if (e >= 150) crazy = 1;
  }
  if (crazy) atomicOr(&red, 1);
  __syncthreads();
  if (threadIdx.x == 0) *flag = red;
}

// ------------------------------------------------------------- small vectors
struct VecArgs {
  const void* src[8];
  int n[8];
  int dstoff[8];
};
__global__ __launch_bounds__(256) void convert_vecs(
    VecArgs a, ushortT* __restrict__ pv, const int* __restrict__ flag) {
  int fl = *flag;
  int t = blockIdx.y;
  int i = blockIdx.x * 256 + threadIdx.x;
  if (i >= a.n[t]) return;
  float v = fl ? ((const float*)a.src[t])[i] : b2f(((const ushortT*)a.src[t])[i]);
  pv[a.dstoff[t] + i] = f2b(v);
}

// ---------------------------------------------------------------- transpose
__global__ __launch_bounds__(256) void transpose_any(
    const void* __restrict__ in, ushortT* __restrict__ out, int K, int N,
    const int* __restrict__ flag) {
  __shared__ ushortT t[32][33];
  int fl = *flag;
  int n0 = blockIdx.x * 32, k0 = blockIdx.y * 32;
  int x = threadIdx.x, y0 = threadIdx.y;
#pragma unroll
  for (int i = y0; i < 32; i += 8) {
    size_t idx = (size_t)(k0 + i) * N + n0 + x;
    t[i][x] = fl ? f2b(((const float*)in)[idx]) : ((const ushortT*)in)[idx];
  }
  __syncthreads();
#pragma unroll
  for (int i = y0; i < 32; i += 8)
    out[(size_t)(n0 + i) * K + k0 + x] = t[x][i];
}

// ------------------------------------------------------- V transpose (attn)
// qkv V-part [b][t][h*64+d] -> vt[bh][d][T]. One block: (bh, 64 t-rows).
__global__ __launch_bounds__(256) void vtrans_kernel(
    const ushortT* __restrict__ qkv, ushortT* __restrict__ vt) {
  const int T = 2048, C3 = 2304;
  __shared__ ushortT tile[64][65];
  int bh = blockIdx.y;
  int b = bh / 12, h = bh % 12;
  int t0 = blockIdx.x * 64;
  int col = threadIdx.x & 63, rowi = threadIdx.x >> 6;
  const ushortT* src = qkv + ((size_t)b * T + t0) * C3 + 1536 + h * 64;
#pragma unroll
  for (int rr = rowi; rr < 64; rr += 4)
    tile[rr][col] = src[(size_t)rr * C3 + col];
  __syncthreads();
#pragma unroll
  for (int dd = rowi; dd < 64; dd += 4)
    vt[((size_t)bh * 64 + dd) * T + t0 + col] = tile[col][dd];
}

// ---------------------------------------------------------------- layernorm
template <int MODE>
__global__ __launch_bounds__(256) void ln_kernel(
    const void* __restrict__ xin, const ushortT* __restrict__ g,
    const ushortT* __restrict__ bb, ushortT* __restrict__ out,
    const int* __restrict__ flag) {
  const int C = 768;
  bool f32;
  if constexpr (MODE == 1) f32 = true; else f32 = (*flag != 0);
  size_t base = (size_t)blockIdx.x * C;
  int tid = threadIdx.x;
  const float* xf = (const float*)xin;
  const ushortT* xb = (const ushortT*)xin;
  float v0 = f32 ? xf[base + tid]       : b2f(xb[base + tid]);
  float v1 = f32 ? xf[base + tid + 256] : b2f(xb[base + tid + 256]);
  float v2 = f32 ? xf[base + tid + 512] : b2f(xb[base + tid + 512]);
  float s = v0 + v1 + v2;
  float q = v0 * v0 + v1 * v1 + v2 * v2;
#pragma unroll
  for (int off = 32; off; off >>= 1) {
    s += __shfl_xor(s, off);
    q += __shfl_xor(q, off);
  }
  __shared__ float as_[4], aq_[4];
  if ((tid & 63) == 0) { as_[tid >> 6] = s; aq_[tid >> 6] = q; }
  __syncthreads();
  s = as_[0] + as_[1] + as_[2] + as_[3];
  q = aq_[0] + aq_[1] + aq_[2] + aq_[3];
  float mu = s * (1.0f / 768.0f);
  float var = q * (1.0f / 768.0f) - mu * mu;
  float rs = rsqrtf(var + 1e-5f);
  ushortT* orow = out + base;
  orow[tid]       = f2b((v0 - mu) * rs * b2f(g[tid])       + b2f(bb[tid]));
  orow[tid + 256] = f2b((v1 - mu) * rs * b2f(g[tid + 256]) + b2f(bb[tid + 256]));
  orow[tid + 512] = f2b((v2 - mu) * rs * b2f(g[tid + 512]) + b2f(bb[tid + 512]));
}

// ---------------------------------------------------------------- GEMM
// C[M,N] = A[M,K] @ Bt[N,K]^T + bias. 128x128 tile, BK=32, 4 waves 2x2.
template <int EPI>
__global__ __launch_bounds__(256) void gemm_bf16(
    const ushortT* __restrict__ A, const ushortT* __restrict__ Bt,
    const ushortT* __restrict__ bias, const void* __restrict__ res,
    void* __restrict__ out, int N, int K, const int* __restrict__ flag) {
  constexpr int LDT = 40;
  __shared__ ushortT As[128 * LDT];
  __shared__ ushortT Bs[128 * LDT];
  int fl = (EPI >= 2) ? *flag : 0;
  int tid = threadIdx.x;
  int lane = tid & 63, wave = tid >> 6;
  int quad = lane >> 4, col = lane & 15;
  int wm = (wave >> 1) << 6, wn = (wave & 1) << 6;
  int m0 = blockIdx.y << 7, n0 = blockIdx.x << 7;

  const ushortT* pa = A + (size_t)(m0 + (tid >> 2)) * K + ((tid & 3) << 3);
  const ushortT* pb = Bt + (size_t)(n0 + (tid >> 2)) * K + ((tid & 3) << 3);
  ushortT* wa = As + (tid >> 2) * LDT + ((tid & 3) << 3);
  ushortT* wb = Bs + (tid >> 2) * LDT + ((tid & 3) << 3);
  size_t rs64 = (size_t)64 * K;

  f32x4 acc[4][4] = {};

  for (int k0 = 0; k0 < K; k0 += 32) {
    uint4 a0 = *(const uint4*)(pa + k0);
    uint4 a1 = *(const uint4*)(pa + rs64 + k0);
    uint4 b0 = *(const uint4*)(pb + k0);
    uint4 b1 = *(const uint4*)(pb + rs64 + k0);
    __syncthreads();
    *(uint4*)wa = a0;
    *(uint4*)(wa + 64 * LDT) = a1;
    *(uint4*)wb = b0;
    *(uint4*)(wb + 64 * LDT) = b1;
    __syncthreads();
    bf16x8 af[4], bfr[4];
#pragma unroll
    for (int mi = 0; mi < 4; ++mi)
      af[mi] = *(const bf16x8*)(As + (wm + mi * 16 + col) * LDT + quad * 8);
#pragma unroll
    for (int ni = 0; ni < 4; ++ni)
      bfr[ni] = *(const bf16x8*)(Bs + (wn + ni * 16 + col) * LDT + quad * 8);
#pragma unroll
    for (int mi = 0; mi < 4; ++mi)
#pragma unroll
      for (int ni = 0; ni < 4; ++ni)
        acc[mi][ni] = MFMA16(af[mi], bfr[ni], acc[mi][ni]);
  }

#pragma unroll
  for (int mi = 0; mi < 4; ++mi) {
#pragma unroll
    for (int ni = 0; ni < 4; ++ni) {
      int gc = n0 + wn + ni * 16 + col;
      float bv = b2f(bias[gc]);
      int gr0 = m0 + wm + mi * 16 + quad * 4;
#pragma unroll
      for (int r = 0; r < 4; ++r) {
        size_t idx = (size_t)(gr0 + r) * N + gc;
        float v = acc[mi][ni][r] + bv;
        if constexpr (EPI == 1) v = gelu_tanh(v);
        if constexpr (EPI == 2) {
          v += fl ? ((const float*)res)[idx] : b2f(((const ushortT*)res)[idx]);
          ((float*)out)[idx] = v;
        } else if constexpr (EPI == 3) {
          v += ((const float*)res)[idx];
          if (fl) ((float*)out)[idx] = v;
          else    ((ushortT*)out)[idx] = f2b(v);
        } else {
          ((ushortT*)out)[idx] = f2b(v);
        }
      }
    }
  }
}

// ---------------------------------------------------------------- attention
// Flash attention, causal. 256 thr = 4 waves; block = 128 q rows (wave: 32),
// 64-key tiles. K frags + V frags (via vt[bh][d][T]) read directly from
// global (16B contiguous). P routed through per-wave LDS (no barriers).
__global__ __launch_bounds__(256) void attn_kernel(
    const ushortT* __restrict__ qkv, const ushortT* __restrict__ vt,
    ushortT* __restrict__ y) {
  const int T = 2048, C3 = 2304;
  constexpr int LDP = 72;
  __shared__ ushortT Ps[4 * 32 * LDP];
  int bh = blockIdx.y;
  int b = bh / 12, h = bh % 12;
  int tid = threadIdx.x;
  int lane = tid & 63, wave = tid >> 6;
  int quad = lane >> 4, n = lane & 15;
  int qw = blockIdx.x * 128 + wave * 32;

  const ushortT* base = qkv + (size_t)b * T * C3;
  const ushortT* kbase = base + 768 + h * 64;
  const ushortT* vbase = vt + (size_t)bh * 64 * T;
  ushortT* myP = Ps + wave * 32 * LDP;

  // Q fragments, pre-scaled by 1/8 (exact exponent shift in bf16 range)
  bf16x8 aq[2][2];
#pragma unroll
  for (int mm = 0; mm < 2; ++mm) {
    const ushortT* qrow =
        base + (size_t)(qw + mm * 16 + n) * C3 + h * 64 + quad * 8;
#pragma unroll
    for (int dh = 0; dh < 2; ++dh) {
      union { ushortT u[8]; bf16x8 v; } tmp;
      const ushortT* p = qrow + dh * 32;
#pragma unroll
      for (int j = 0; j < 8; ++j) tmp.u[j] = f2b(b2f(p[j]) * 0.125f);
      aq[mm][dh] = tmp.v;
    }
  }

  f32x4 O[2][4] = {};
  float mrow[2][4], lrow[2][4];
#pragma unroll
  for (int mm = 0; mm < 2; ++mm)
#pragma unroll
    for (int r = 0; r < 4; ++r) { mrow[mm][r] = -1e30f; lrow[mm][r] = 0.f; }

  int ntiles = (qw + 95) >> 6;
  for (int kt = 0; kt < ntiles; ++kt) {
    int k0 = kt << 6;
    // ---- S = (Q/8) K^T
    f32x4 S[2][4];
    const ushortT* kp = kbase + (size_t)(k0 + n) * C3 + quad * 8;
#pragma unroll
    for (int g = 0; g < 4; ++g) {
      bf16x8 kb0 = *(const bf16x8*)(kp + (size_t)g * 16 * C3);
      bf16x8 kb1 = *(const bf16x8*)(kp + (size_t)g * 16 * C3 + 32);
#pragma unroll
      for (int mm = 0; mm < 2; ++mm) {
        f32x4 z = {};
        z = MFMA16(aq[mm][0], kb0, z);
        S[mm][g] = MFMA16(aq[mm][1], kb1, z);
      }
    }
    // ---- online softmax (per 16-lane row groups)
    bool full = (k0 + 63 <= qw);
#pragma unroll
    for (int mm = 0; mm < 2; ++mm) {
#pragma unroll
      for (int r = 0; r < 4; ++r) {
        float s0 = S[mm][0][r], s1 = S[mm][1][r],
              s2 = S[mm][2][r], s3 = S[mm][3][r];
        if (!full) {
          int lim = qw + mm * 16 + quad * 4 + r - k0;
          s0 = (n <= lim) ? s0 : -1e30f;
          s1 = (n + 16 <= lim) ? s1 : -1e30f;
          s2 = (n + 32 <= lim) ? s2 : -1e30f;
          s3 = (n + 48 <= lim) ? s3 : -1e30f;
        }
        float lm = fmaxf(fmaxf(s0, s1), fmaxf(s2, s3));
#pragma unroll
        for (int off = 8; off; off >>= 1) lm = fmaxf(lm, __shfl_xor(lm, off));
        float mn = fmaxf(mrow[mm][r], lm);
        float alpha = __expf(mrow[mm][r] - mn);
        mrow[mm][r] = mn;
        float p0 = __expf(s0 - mn), p1 = __expf(s1 - mn),
              p2 = __expf(s2 - mn), p3 = __expf(s3 - mn);
        float ls = (p0 + p1) + (p2 + p3);
#pragma unroll
        for (int off = 8; off; off >>= 1) ls += __shfl_xor(ls, off);
        lrow[mm][r] = lrow[mm][r] * alpha + ls;
        O[mm][0][r] *= alpha; O[mm][1][r] *= alpha;
        O[mm][2][r] *= alpha; O[mm][3][r] *= alpha;
        ushortT* pw = myP + (mm * 16 + quad * 4 + r) * LDP + n;
        pw[0] = f2b(p0); pw[16] = f2b(p1); pw[32] = f2b(p2); pw[48] = f2b(p3);
      }
    }
    // ---- O += P V   (P a-frags from LDS, V b-frags from vt, contiguous)
    bf16x8 pa[2][2];
#pragma unroll
    for (int mm = 0; mm < 2; ++mm) {
      pa[mm][0] = *(const bf16x8*)(myP + (mm * 16 + n) * LDP + quad * 8);
      pa[mm][1] = *(const bf16x8*)(myP + (mm * 16 + n) * LDP + 32 + quad * 8);
    }
#pragma unroll
    for (int dt = 0; dt < 4; ++dt) {
      const ushortT* vp = vbase + (size_t)(dt * 16 + n) * T + k0 + quad * 8;
      bf16x8 vb0 = *(const bf16x8*)vp;
      bf16x8 vb1 = *(const bf16x8*)(vp + 32);
#pragma unroll
      for (int mm = 0; mm < 2; ++mm) {
        O[mm][dt] = MFMA16(pa[mm][0], vb0, O[mm][dt]);
        O[mm][dt] = MFMA16(pa[mm][1], vb1, O[mm][dt]);
      }
    }
  }
  // ---- epilogue
#pragma unroll
  for (int mm = 0; mm < 2; ++mm)
#pragma unroll
    for (int dt = 0; dt < 4; ++dt)
#pragma unroll
      for (int r = 0; r < 4; ++r) {
        int qg = qw + mm * 16 + quad * 4 + r;
        y[(size_t)(b * T + qg) * 768 + h * 64 + dt * 16 + n] =
            f2b(O[mm][dt][r] / lrow[mm][r]);
      }
}

// ---------------------------------------------------------------- launch
extern "C" void kernel_launch(void* const* d_in, const int* in_sizes, int n_in,
                              void* d_out, int out_size, void* d_ws,
                              size_t ws_size, hipStream_t stream) {
  (void)in_sizes; (void)n_in; (void)out_size; (void)ws_size;
  const void* x       = d_in[0];
  const void* w_attn  = d_in[3];
  const void* w_aproj = d_in[5];
  const void* w_fc    = d_in[9];
  const void* w_mproj = d_in[11];

  char* ws = (char*)d_ws;
  ushortT* h1  = (ushortT*)(ws);                 // [8192,768] bf16; later vt
  ushortT* qkv = (ushortT*)(ws + 12582912);      // [8192,2304] bf16
  ushortT* yb  = (ushortT*)(ws + 50331648);      // [8192,768] bf16; later h2
  float*   x1  = (float*)(ws + 62914560);        // [8192,768] fp32
  ushortT* fcg = (ushortT*)(ws + 88080384);      // [8192,3072] bf16
  ushortT* wT0 = (ushortT*)(ws + 138412032);     // w_attn^T  [2304,768]
  ushortT* wT1 = (ushortT*)(ws + 141950976);     // w_aproj^T [768,768]
  ushortT* wT2 = (ushortT*)(ws + 143130624);     // w_fc^T    [3072,768]
  ushortT* wT3 = (ushortT*)(ws + 147849216);     // w_mproj^T [768,3072]
  ushortT* pv  = (ushortT*)(ws + 152567808);     // packed vectors (bf16)
  int*     flag = (int*)(ws + 152600576);
  ushortT* vt  = h1;   // [48][64][2048] bf16 = 12.58MB, h1 dead after qkv GEMM
  ushortT* h2  = yb;   // yb dead after aproj GEMM

  const int O_LN1G = 0, O_LN1B = 768, O_BATT = 1536, O_BAPR = 3840,
            O_LN2G = 4608, O_LN2B = 5376, O_BFC = 6144, O_BMPR = 9216;

  detect_dtype<<<1, 256, 0, stream>>>((const ushortT*)w_fc, flag);

  VecArgs va;
  va.src[0] = d_in[1];  va.n[0] = 768;  va.dstoff[0] = O_LN1G;
  va.src[1] = d_in[2];  va.n[1] = 768;  va.dstoff[1] = O_LN1B;
  va.src[2] = d_in[4];  va.n[2] = 2304; va.dstoff[2] = O_BATT;
  va.src[3] = d_in[6];  va.n[3] = 768;  va.dstoff[3] = O_BAPR;
  va.src[4] = d_in[7];  va.n[4] = 768;  va.dstoff[4] = O_LN2G;
  va.src[5] = d_in[8];  va.n[5] = 768;  va.dstoff[5] = O_LN2B;
  va.src[6] = d_in[10]; va.n[6] = 3072; va.dstoff[6] = O_BFC;
  va.src[7] = d_in[12]; va.n[7] = 768;  va.dstoff[7] = O_BMPR;
  convert_vecs<<<dim3(12, 8), 256, 0, stream>>>(va, pv, flag);

  dim3 tb(32, 8);
  transpose_any<<<dim3(72, 24), tb, 0, stream>>>(w_attn, wT0, 768, 2304, flag);
  transpose_any<<<dim3(24, 24), tb, 0, stream>>>(w_aproj, wT1, 768, 768, flag);
  transpose_any<<<dim3(96, 24), tb, 0, stream>>>(w_fc, wT2, 768, 3072, flag);
  transpose_any<<<dim3(24, 96), tb, 0, stream>>>(w_mproj, wT3, 3072, 768, flag);

  ln_kernel<0><<<8192, 256, 0, stream>>>(x, pv + O_LN1G, pv + O_LN1B, h1, flag);
  gemm_bf16<0><<<dim3(18, 64), 256, 0, stream>>>(h1, wT0, pv + O_BATT, nullptr,
                                                 qkv, 2304, 768, flag);
  vtrans_kernel<<<dim3(32, 48), 256, 0, stream>>>(qkv, vt);
  attn_kernel<<<dim3(16, 48), 256, 0, stream>>>(qkv, vt, yb);
  gemm_bf16<2><<<dim3(6, 64), 256, 0, stream>>>(yb, wT1, pv + O_BAPR, x, x1,
                                                768, 768, flag);
  ln_kernel<1><<<8192, 256, 0, stream>>>(x1, pv + O_LN2G, pv + O_LN2B, h2, flag);
  gemm_bf16<1><<<dim3(24, 64), 256, 0, stream>>>(h2, wT2, pv + O_BFC, nullptr,
                                                 fcg, 3072, 768, flag);
  gemm_bf16<3><<<dim3(6, 64), 256, 0, stream>>>(fcg, wT3, pv + O_BMPR, x1,
                                                d_out, 768, 3072, flag);
}

// Round 4
// 498.557 us; speedup vs baseline: 1.4539x; 1.4539x over previous
//
#include <hip/hip_runtime.h>

// GPT-2 block forward, MI355X/gfx950. B=4 T=2048 C=768 H=12 D=64; M=8192.
// R4: flash attention with block-level K/V LDS staging, S^T/O^T MFMA
// orientation (softmax at q=lane&15: 2-shuffle reductions), causal-balance
// swizzle. GEMM: register prefetch of next k-tile.

typedef unsigned short ushortT;
typedef unsigned int uintT;
typedef __attribute__((ext_vector_type(8))) __bf16 bf16x8;
typedef __attribute__((ext_vector_type(4))) float f32x4;

#define MFMA16(a, b, c) __builtin_amdgcn_mfma_f32_16x16x32_bf16(a, b, c, 0, 0, 0)

__device__ inline float b2f(ushortT u) {
  return __uint_as_float(((uintT)u) << 16);
}
__device__ inline ushortT f2b(float f) {  // round-to-nearest-even
  uintT x = __float_as_uint(f);
  uintT r = x + 0x7fffu + ((x >> 16) & 1u);
  return (ushortT)(r >> 16);
}

__device__ inline float gelu_tanh(float v) {
  float t = 0.7978845608028654f * (v + 0.044715f * v * v * v);
  return v / (1.0f + __expf(-2.0f * t));
}

// ------------------------------------------------------------- dtype detect
__global__ __launch_bounds__(256) void detect_dtype(
    const ushortT* __restrict__ w, int* __restrict__ flag) {
  __shared__ int red;
  if (threadIdx.x == 0) red = 0;
  __syncthreads();
  int crazy = 0;
  for (int i = threadIdx.x; i < 4096; i += 256) {
    uintT e = (w[2 * i] >> 7) & 0xFF;
    if (e >= 150) crazy = 1;
  }
  if (crazy) atomicOr(&red, 1);
  __syncthreads();
  if (threadIdx.x == 0) *flag = red;
}

// ------------------------------------------------------------- small vectors
struct VecArgs {
  const void* src[8];
  int n[8];
  int dstoff[8];
};
__global__ __launch_bounds__(256) void convert_vecs(
    VecArgs a, ushortT* __restrict__ pv, const int* __restrict__ flag) {
  int fl = *flag;
  int t = blockIdx.y;
  int i = blockIdx.x * 256 + threadIdx.x;
  if (i >= a.n[t]) return;
  float v = fl ? ((const float*)a.src[t])[i] : b2f(((const ushortT*)a.src[t])[i]);
  pv[a.dstoff[t] + i] = f2b(v);
}

// ---------------------------------------------------------------- transpose
__global__ __launch_bounds__(256) void transpose_any(
    const void* __restrict__ in, ushortT* __restrict__ out, int K, int N,
    const int* __restrict__ flag) {
  __shared__ ushortT t[32][33];
  int fl = *flag;
  int n0 = blockIdx.x * 32, k0 = blockIdx.y * 32;
  int x = threadIdx.x, y0 = threadIdx.y;
#pragma unroll
  for (int i = y0; i < 32; i += 8) {
    size_t idx = (size_t)(k0 + i) * N + n0 + x;
    t[i][x] = fl ? f2b(((const float*)in)[idx]) : ((const ushortT*)in)[idx];
  }
  __syncthreads();
#pragma unroll
  for (int i = y0; i < 32; i += 8)
    out[(size_t)(n0 + i) * K + k0 + x] = t[x][i];
}

// ------------------------------------------------------- V transpose (attn)
// qkv V-part [b][t][h*64+d] -> vt[bh][d][T].
__global__ __launch_bounds__(256) void vtrans_kernel(
    const ushortT* __restrict__ qkv, ushortT* __restrict__ vt) {
  const int T = 2048, C3 = 2304;
  __shared__ ushortT tile[64][65];
  int bh = blockIdx.y;
  int b = bh / 12, h = bh % 12;
  int t0 = blockIdx.x * 64;
  int col = threadIdx.x & 63, rowi = threadIdx.x >> 6;
  const ushortT* src = qkv + ((size_t)b * T + t0) * C3 + 1536 + h * 64;
#pragma unroll
  for (int rr = rowi; rr < 64; rr += 4)
    tile[rr][col] = src[(size_t)rr * C3 + col];
  __syncthreads();
#pragma unroll
  for (int dd = rowi; dd < 64; dd += 4)
    vt[((size_t)bh * 64 + dd) * T + t0 + col] = tile[col][dd];
}

// ---------------------------------------------------------------- layernorm
template <int MODE>
__global__ __launch_bounds__(256) void ln_kernel(
    const void* __restrict__ xin, const ushortT* __restrict__ g,
    const ushortT* __restrict__ bb, ushortT* __restrict__ out,
    const int* __restrict__ flag) {
  const int C = 768;
  bool f32;
  if constexpr (MODE == 1) f32 = true; else f32 = (*flag != 0);
  size_t base = (size_t)blockIdx.x * C;
  int tid = threadIdx.x;
  const float* xf = (const float*)xin;
  const ushortT* xb = (const ushortT*)xin;
  float v0 = f32 ? xf[base + tid]       : b2f(xb[base + tid]);
  float v1 = f32 ? xf[base + tid + 256] : b2f(xb[base + tid + 256]);
  float v2 = f32 ? xf[base + tid + 512] : b2f(xb[base + tid + 512]);
  float s = v0 + v1 + v2;
  float q = v0 * v0 + v1 * v1 + v2 * v2;
#pragma unroll
  for (int off = 32; off; off >>= 1) {
    s += __shfl_xor(s, off);
    q += __shfl_xor(q, off);
  }
  __shared__ float as_[4], aq_[4];
  if ((tid & 63) == 0) { as_[tid >> 6] = s; aq_[tid >> 6] = q; }
  __syncthreads();
  s = as_[0] + as_[1] + as_[2] + as_[3];
  q = aq_[0] + aq_[1] + aq_[2] + aq_[3];
  float mu = s * (1.0f / 768.0f);
  float var = q * (1.0f / 768.0f) - mu * mu;
  float rs = rsqrtf(var + 1e-5f);
  ushortT* orow = out + base;
  orow[tid]       = f2b((v0 - mu) * rs * b2f(g[tid])       + b2f(bb[tid]));
  orow[tid + 256] = f2b((v1 - mu) * rs * b2f(g[tid + 256]) + b2f(bb[tid + 256]));
  orow[tid + 512] = f2b((v2 - mu) * rs * b2f(g[tid + 512]) + b2f(bb[tid + 512]));
}

// ---------------------------------------------------------------- GEMM
// C[M,N] = A[M,K] @ Bt[N,K]^T + bias. 128x128 tile, BK=32, 4 waves 2x2.
// Register prefetch of next k-tile overlaps global latency with MFMA.
template <int EPI>
__global__ __launch_bounds__(256) void gemm_bf16(
    const ushortT* __restrict__ A, const ushortT* __restrict__ Bt,
    const ushortT* __restrict__ bias, const void* __restrict__ res,
    void* __restrict__ out, int N, int K, const int* __restrict__ flag) {
  constexpr int LDT = 40;
  __shared__ ushortT As[128 * LDT];
  __shared__ ushortT Bs[128 * LDT];
  int fl = (EPI >= 2) ? *flag : 0;
  int tid = threadIdx.x;
  int lane = tid & 63, wave = tid >> 6;
  int quad = lane >> 4, col = lane & 15;
  int wm = (wave >> 1) << 6, wn = (wave & 1) << 6;
  int m0 = blockIdx.y << 7, n0 = blockIdx.x << 7;

  const ushortT* pa = A + (size_t)(m0 + (tid >> 2)) * K + ((tid & 3) << 3);
  const ushortT* pb = Bt + (size_t)(n0 + (tid >> 2)) * K + ((tid & 3) << 3);
  ushortT* wa = As + (tid >> 2) * LDT + ((tid & 3) << 3);
  ushortT* wb = Bs + (tid >> 2) * LDT + ((tid & 3) << 3);
  size_t rs64 = (size_t)64 * K;

  f32x4 acc[4][4] = {};
  uint4 a0 = *(const uint4*)(pa);
  uint4 a1 = *(const uint4*)(pa + rs64);
  uint4 b0 = *(const uint4*)(pb);
  uint4 b1 = *(const uint4*)(pb + rs64);

  for (int k0 = 0; k0 < K; k0 += 32) {
    __syncthreads();
    *(uint4*)wa = a0;
    *(uint4*)(wa + 64 * LDT) = a1;
    *(uint4*)wb = b0;
    *(uint4*)(wb + 64 * LDT) = b1;
    __syncthreads();
    if (k0 + 32 < K) {
      a0 = *(const uint4*)(pa + k0 + 32);
      a1 = *(const uint4*)(pa + rs64 + k0 + 32);
      b0 = *(const uint4*)(pb + k0 + 32);
      b1 = *(const uint4*)(pb + rs64 + k0 + 32);
    }
    bf16x8 af[4], bfr[4];
#pragma unroll
    for (int mi = 0; mi < 4; ++mi)
      af[mi] = *(const bf16x8*)(As + (wm + mi * 16 + col) * LDT + quad * 8);
#pragma unroll
    for (int ni = 0; ni < 4; ++ni)
      bfr[ni] = *(const bf16x8*)(Bs + (wn + ni * 16 + col) * LDT + quad * 8);
#pragma unroll
    for (int mi = 0; mi < 4; ++mi)
#pragma unroll
      for (int ni = 0; ni < 4; ++ni)
        acc[mi][ni] = MFMA16(af[mi], bfr[ni], acc[mi][ni]);
  }

#pragma unroll
  for (int mi = 0; mi < 4; ++mi) {
#pragma unroll
    for (int ni = 0; ni < 4; ++ni) {
      int gc = n0 + wn + ni * 16 + col;
      float bv = b2f(bias[gc]);
      int gr0 = m0 + wm + mi * 16 + quad * 4;
#pragma unroll
      for (int r = 0; r < 4; ++r) {
        size_t idx = (size_t)(gr0 + r) * N + gc;
        float v = acc[mi][ni][r] + bv;
        if constexpr (EPI == 1) v = gelu_tanh(v);
        if constexpr (EPI == 2) {
          v += fl ? ((const float*)res)[idx] : b2f(((const ushortT*)res)[idx]);
          ((float*)out)[idx] = v;
        } else if constexpr (EPI == 3) {
          v += ((const float*)res)[idx];
          if (fl) ((float*)out)[idx] = v;
          else    ((ushortT*)out)[idx] = f2b(v);
        } else {
          ((ushortT*)out)[idx] = f2b(v);
        }
      }
    }
  }
}

// ---------------------------------------------------------------- attention
// Flash, causal. Block = 256 thr (4 waves) x 128 q-rows; 64-key tiles staged
// in LDS (K[key][d], V^T[d][key]) with register prefetch. S^T = K Q^T and
// O^T = V^T P^T so softmax state sits at q = lane&15 (2-shuffle reductions,
// shuffle-free O rescale). Per-wave P buffer, b64-packed writes.
__global__ __launch_bounds__(256) void attn_kernel(
    const ushortT* __restrict__ qkv, const ushortT* __restrict__ vt,
    ushortT* __restrict__ y) {
  const int T = 2048, C3 = 2304;
  constexpr int LDK = 72, LDP = 72;
  __shared__ ushortT Ks[64 * LDK];
  __shared__ ushortT Vs[64 * LDK];
  __shared__ ushortT Ps[4 * 32 * LDP];
  int bh = blockIdx.y;
  int b = bh / 12, h = bh % 12;
  int qt = (int)((blockIdx.x * 5 + blockIdx.y) & 15);  // balance swizzle
  int tid = threadIdx.x;
  int lane = tid & 63, wave = tid >> 6;
  int quad = lane >> 4, n = lane & 15;
  int qw = qt * 128 + wave * 32;

  const ushortT* base = qkv + (size_t)b * T * C3;
  const ushortT* kbase = base + 768 + h * 64;
  const ushortT* vbase = vt + (size_t)bh * 64 * T;
  ushortT* myP = Ps + wave * 32 * LDP;

  // Q fragments (B-operand of S^T = K Q^T), pre-scaled by 1/8
  bf16x8 aq[2][2];
#pragma unroll
  for (int mm = 0; mm < 2; ++mm) {
    const ushortT* qrow =
        base + (size_t)(qw + mm * 16 + n) * C3 + h * 64 + quad * 8;
#pragma unroll
    for (int dh = 0; dh < 2; ++dh) {
      union { ushortT u[8]; bf16x8 v; } tmp;
      const ushortT* p = qrow + dh * 32;
#pragma unroll
      for (int j = 0; j < 8; ++j) tmp.u[j] = f2b(b2f(p[j]) * 0.125f);
      aq[mm][dh] = tmp.v;
    }
  }

  f32x4 Ot[2][4] = {};  // O^T[d][q]: lane q=n, d = dt*16 + quad*4 + r
  float mrow[2] = {-1e30f, -1e30f}, lrow[2] = {0.f, 0.f};

  int ntb = 2 * qt + 2;  // k-tiles for the whole block
  int trow = tid >> 3, tcol = (tid & 7) << 3;
  const ushortT* kg = kbase + (size_t)trow * C3 + tcol;
  const ushortT* vg = vbase + (size_t)trow * T + tcol;
  uint4 kr0 = *(const uint4*)(kg);
  uint4 kr1 = *(const uint4*)(kg + (size_t)32 * C3);
  uint4 vr0 = *(const uint4*)(vg);
  uint4 vr1 = *(const uint4*)(vg + (size_t)32 * T);

  for (int kt = 0; kt < ntb; ++kt) {
    int k0 = kt << 6;
    __syncthreads();
    *(uint4*)(Ks + trow * LDK + tcol) = kr0;
    *(uint4*)(Ks + (trow + 32) * LDK + tcol) = kr1;
    *(uint4*)(Vs + trow * LDK + tcol) = vr0;
    *(uint4*)(Vs + (trow + 32) * LDK + tcol) = vr1;
    __syncthreads();
    if (kt + 1 < ntb) {
      int k0n = (kt + 1) << 6;
      kr0 = *(const uint4*)(kg + (size_t)k0n * C3);
      kr1 = *(const uint4*)(kg + (size_t)(k0n + 32) * C3);
      vr0 = *(const uint4*)(vg + k0n);
      vr1 = *(const uint4*)(vg + (size_t)32 * T + k0n);
    }
    if (k0 > qw + 31) continue;  // uniform per wave; barriers already done

    // ---- S^T = K (Q/8)^T : A = K-frag from LDS, B = aq
    f32x4 St[2][4];
#pragma unroll
    for (int g = 0; g < 4; ++g) {
      bf16x8 ka0 = *(const bf16x8*)(Ks + (g * 16 + n) * LDK + quad * 8);
      bf16x8 ka1 = *(const bf16x8*)(Ks + (g * 16 + n) * LDK + 32 + quad * 8);
#pragma unroll
      for (int mm = 0; mm < 2; ++mm) {
        f32x4 z = {};
        z = MFMA16(ka0, aq[mm][0], z);
        St[mm][g] = MFMA16(ka1, aq[mm][1], z);
      }
    }
    // ---- online softmax at q = n (+16*mm); keys live in regs (g,quad,r)
    bool act[2];
#pragma unroll
    for (int mm = 0; mm < 2; ++mm) {
      act[mm] = (k0 <= qw + mm * 16 + 15);
      if (!act[mm]) continue;
      int lim = qw + mm * 16 + n - k0;  // key-offset causal limit
      bool full = (k0 + 63 <= qw + mm * 16);
      float lm = -1e30f;
#pragma unroll
      for (int g = 0; g < 4; ++g)
#pragma unroll
        for (int r = 0; r < 4; ++r) {
          float s = St[mm][g][r];
          if (!full && (g * 16 + quad * 4 + r > lim)) s = -1e30f;
          St[mm][g][r] = s;
          lm = fmaxf(lm, s);
        }
      lm = fmaxf(lm, __shfl_xor(lm, 16));
      lm = fmaxf(lm, __shfl_xor(lm, 32));
      float mn = fmaxf(mrow[mm], lm);
      float alpha = __expf(mrow[mm] - mn);
      mrow[mm] = mn;
      float ls = 0.f;
#pragma unroll
      for (int g = 0; g < 4; ++g) {
        ushort4 pk;
        float p0 = __expf(St[mm][g][0] - mn);
        float p1 = __expf(St[mm][g][1] - mn);
        float p2 = __expf(St[mm][g][2] - mn);
        float p3 = __expf(St[mm][g][3] - mn);
        ls += (p0 + p1) + (p2 + p3);
        pk.x = f2b(p0); pk.y = f2b(p1); pk.z = f2b(p2); pk.w = f2b(p3);
        *(ushort4*)(myP + (mm * 16 + n) * LDP + g * 16 + quad * 4) = pk;
      }
      ls += __shfl_xor(ls, 16);
      ls += __shfl_xor(ls, 32);
      lrow[mm] = lrow[mm] * alpha + ls;
#pragma unroll
      for (int dt = 0; dt < 4; ++dt)
#pragma unroll
        for (int r = 0; r < 4; ++r) Ot[mm][dt][r] *= alpha;
    }
    // ---- O^T += V^T P^T : A = V^T-frag from LDS, B = P-frag from LDS
    bf16x8 pb[2][2];
#pragma unroll
    for (int mm = 0; mm < 2; ++mm)
      if (act[mm]) {
        pb[mm][0] = *(const bf16x8*)(myP + (mm * 16 + n) * LDP + quad * 8);
        pb[mm][1] = *(const bf16x8*)(myP + (mm * 16 + n) * LDP + 32 + quad * 8);
      }
#pragma unroll
    for (int dt = 0; dt < 4; ++dt) {
      bf16x8 va0 = *(const bf16x8*)(Vs + (dt * 16 + n) * LDK + quad * 8);
      bf16x8 va1 = *(const bf16x8*)(Vs + (dt * 16 + n) * LDK + 32 + quad * 8);
#pragma unroll
      for (int mm = 0; mm < 2; ++mm)
        if (act[mm]) {
          Ot[mm][dt] = MFMA16(va0, pb[mm][0], Ot[mm][dt]);
          Ot[mm][dt] = MFMA16(va1, pb[mm][1], Ot[mm][dt]);
        }
    }
  }
  // ---- epilogue: O = O^T / l, packed 8B stores
#pragma unroll
  for (int mm = 0; mm < 2; ++mm) {
    float inv = 1.0f / lrow[mm];
    int qg = qw + mm * 16 + n;
#pragma unroll
    for (int dt = 0; dt < 4; ++dt) {
      ushort4 o;
      o.x = f2b(Ot[mm][dt][0] * inv);
      o.y = f2b(Ot[mm][dt][1] * inv);
      o.z = f2b(Ot[mm][dt][2] * inv);
      o.w = f2b(Ot[mm][dt][3] * inv);
      *(ushort4*)(y + (size_t)(b * T + qg) * 768 + h * 64 + dt * 16 +
                  quad * 4) = o;
    }
  }
}

// ---------------------------------------------------------------- launch
extern "C" void kernel_launch(void* const* d_in, const int* in_sizes, int n_in,
                              void* d_out, int out_size, void* d_ws,
                              size_t ws_size, hipStream_t stream) {
  (void)in_sizes; (void)n_in; (void)out_size; (void)ws_size;
  const void* x       = d_in[0];
  const void* w_attn  = d_in[3];
  const void* w_aproj = d_in[5];
  const void* w_fc    = d_in[9];
  const void* w_mproj = d_in[11];

  char* ws = (char*)d_ws;
  ushortT* h1  = (ushortT*)(ws);                 // [8192,768] bf16; later vt
  ushortT* qkv = (ushortT*)(ws + 12582912);      // [8192,2304] bf16
  ushortT* yb  = (ushortT*)(ws + 50331648);      // [8192,768] bf16; later h2
  float*   x1  = (float*)(ws + 62914560);        // [8192,768] fp32
  ushortT* fcg = (ushortT*)(ws + 88080384);      // [8192,3072] bf16
  ushortT* wT0 = (ushortT*)(ws + 138412032);     // w_attn^T  [2304,768]
  ushortT* wT1 = (ushortT*)(ws + 141950976);     // w_aproj^T [768,768]
  ushortT* wT2 = (ushortT*)(ws + 143130624);     // w_fc^T    [3072,768]
  ushortT* wT3 = (ushortT*)(ws + 147849216);     // w_mproj^T [768,3072]
  ushortT* pv  = (ushortT*)(ws + 152567808);     // packed vectors (bf16)
  int*     flag = (int*)(ws + 152600576);
  ushortT* vt  = h1;   // [48][64][2048] bf16, h1 dead after qkv GEMM
  ushortT* h2  = yb;   // yb dead after aproj GEMM

  const int O_LN1G = 0, O_LN1B = 768, O_BATT = 1536, O_BAPR = 3840,
            O_LN2G = 4608, O_LN2B = 5376, O_BFC = 6144, O_BMPR = 9216;

  detect_dtype<<<1, 256, 0, stream>>>((const ushortT*)w_fc, flag);

  VecArgs va;
  va.src[0] = d_in[1];  va.n[0] = 768;  va.dstoff[0] = O_LN1G;
  va.src[1] = d_in[2];  va.n[1] = 768;  va.dstoff[1] = O_LN1B;
  va.src[2] = d_in[4];  va.n[2] = 2304; va.dstoff[2] = O_BATT;
  va.src[3] = d_in[6];  va.n[3] = 768;  va.dstoff[3] = O_BAPR;
  va.src[4] = d_in[7];  va.n[4] = 768;  va.dstoff[4] = O_LN2G;
  va.src[5] = d_in[8];  va.n[5] = 768;  va.dstoff[5] = O_LN2B;
  va.src[6] = d_in[10]; va.n[6] = 3072; va.dstoff[6] = O_BFC;
  va.src[7] = d_in[12]; va.n[7] = 768;  va.dstoff[7] = O_BMPR;
  convert_vecs<<<dim3(12, 8), 256, 0, stream>>>(va, pv, flag);

  dim3 tb(32, 8);
  transpose_any<<<dim3(72, 24), tb, 0, stream>>>(w_attn, wT0, 768, 2304, flag);
  transpose_any<<<dim3(24, 24), tb, 0, stream>>>(w_aproj, wT1, 768, 768, flag);
  transpose_any<<<dim3(96, 24), tb, 0, stream>>>(w_fc, wT2, 768, 3072, flag);
  transpose_any<<<dim3(24, 96), tb, 0, stream>>>(w_mproj, wT3, 3072, 768, flag);

  ln_kernel<0><<<8192, 256, 0, stream>>>(x, pv + O_LN1G, pv + O_LN1B, h1, flag);
  gemm_bf16<0><<<dim3(18, 64), 256, 0, stream>>>(h1, wT0, pv + O_BATT, nullptr,
                                                 qkv, 2304, 768, flag);
  vtrans_kernel<<<dim3(32, 48), 256, 0, stream>>>(qkv, vt);
  attn_kernel<<<dim3(16, 48), 256, 0, stream>>>(qkv, vt, yb);
  gemm_bf16<2><<<dim3(6, 64), 256, 0, stream>>>(yb, wT1, pv + O_BAPR, x, x1,
                                                768, 768, flag);
  ln_kernel<1><<<8192, 256, 0, stream>>>(x1, pv + O_LN2G, pv + O_LN2B, h2, flag);
  gemm_bf16<1><<<dim3(24, 64), 256, 0, stream>>>(h2, wT2, pv + O_BFC, nullptr,
                                                 fcg, 3072, 768, flag);
  gemm_bf16<3><<<dim3(6, 64), 256, 0, stream>>>(fcg, wT3, pv + O_BMPR, x1,
                                                d_out, 768, 3072, flag);
}